// Round 11
// baseline (207.879 us; speedup 1.0000x reference)
//
#include <hip/hip_runtime.h>
#include <hip/hip_bf16.h>
#include <stdint.h>

typedef short bf16x8 __attribute__((ext_vector_type(8)));
typedef float f32x16 __attribute__((ext_vector_type(16)));

#define T 2048
#define KLEN 2049
#define DK 32
#define NCO 32
#define NCI 32
#define NB 32

#define GR 2216          // padded reversed row length (covers g up to 2184)
#define SREF 2055        // x[s] lives at g = SREF - s (xr); xrs[g] = xr[g+1]
#define WT_CH 257        // 8-wide d-chunks, d in [0,2056)
#define WT_ELEMS (NCI*WT_CH*NCO*8)
#define XR_ELEMS (NB*NCI*GR)

#define WT_OFF 0
#define XR_OFF (WT_ELEMS*2)
#define XRS_OFF (XR_OFF + XR_ELEMS*2)

#define CIB 528          // bytes per ci row: 33 x 16B granules (264 elems)
#define GPC 1056         // real granules per parity copy (32 ci x 33)
#define GPCP 1088        // padded to 17 x 64-chunks (no copy-straddle)
#define CPYB 17472       // parity-copy stride: >=GPCP*16, ==64 mod 128 (bank de-alias)
#define BUFB (2*CPYB)    // 34944 per double-buffer
#define LDS_TOT (2*BUFB) // 69888 -> 2 blocks/CU; reduce reuses buf0

// ---------------- kernel-generation: SIREN -> flipped, fragment-layout W ----
__global__ __launch_bounds__(256) void gen_w(
    const float* __restrict__ rel_pos,
    const float* __restrict__ w1, const float* __restrict__ b1, const float* __restrict__ om1,
    const float* __restrict__ w2, const float* __restrict__ b2, const float* __restrict__ om2,
    const float* __restrict__ w3, const float* __restrict__ b3,
    uint16_t* __restrict__ Wt)
{
    int d = blockIdx.x;          // flipped lag, 0..2055
    int tid = threadIdx.x;
    if (d >= KLEN) {             // zero pad region
        for (int r = 0; r < 4; ++r) {
            int coci = tid + 256*r;
            int co = coci >> 5, ci = coci & 31;
            Wt[(((ci*WT_CH + (d>>3))*NCO + co)<<3) + (d&7)] = 0;
        }
        return;
    }
    int kk = 2048 - d;
    float pos = rel_pos[kk];
    __shared__ float h1[DK];
    __shared__ float h2[DK];
    if (tid < DK) h1[tid] = sinf(om1[0]*(w1[tid]*pos + b1[tid]));
    __syncthreads();
    if (tid < DK) {
        float a = b2[tid];
        for (int j = 0; j < DK; ++j) a += w2[tid*DK+j]*h1[j];
        h2[tid] = sinf(om2[0]*a);
    }
    __syncthreads();
    for (int r = 0; r < 4; ++r) {
        int coci = tid + 256*r;
        float a = b3[coci];
        for (int j = 0; j < DK; ++j) a += w3[coci*DK+j]*h2[j];
        int co = coci >> 5, ci = coci & 31;
        __hip_bfloat16 hv = __float2bfloat16(a);
        Wt[(((ci*WT_CH + (d>>3))*NCO + co)<<3) + (d&7)] = *(uint16_t*)&hv;
    }
}

// ---------------- x -> reversed, zero-padded bf16 (plus shifted copy) -------
__global__ __launch_bounds__(256) void gen_x(const float* __restrict__ x,
                                             uint16_t* __restrict__ xr,
                                             uint16_t* __restrict__ xrs)
{
    int idx = blockIdx.x*256 + threadIdx.x;
    if (idx >= NB*NCI*GR) return;
    int row = idx / GR;          // b*32+ci
    int g = idx - row*GR;
    int s = SREF - g;
    float v  = (s  >= 0 && s  < T) ? x[row*T + s]  : 0.f;
    int s2 = s - 1;              // value at g+1
    float v2 = (s2 >= 0 && s2 < T) ? x[row*T + s2] : 0.f;
    __hip_bfloat16 hv = __float2bfloat16(v);
    __hip_bfloat16 hv2 = __float2bfloat16(v2);
    xr[idx]  = *(uint16_t*)&hv;
    xrs[idx] = *(uint16_t*)&hv2;
}

// ---------------- out <- bias (conv blocks atomically accumulate) ----------
__global__ __launch_bounds__(256) void init_out(const float* __restrict__ bias,
                                                float* __restrict__ out)
{
    int i = blockIdx.x*256 + threadIdx.x;   // NB*NCO*T = 2097152
    out[i] = bias[(i >> 11) & 31];
}

__device__ __forceinline__ void gld16(const uint16_t* g, char* l)
{
    typedef const __attribute__((address_space(1))) uint32_t GU;
    typedef __attribute__((address_space(3))) uint32_t LU;
    __builtin_amdgcn_global_load_lds((GU*)g, (LU*)l, 16, 0, 0);
}

// ---------------- causal conv: implicit-Toeplitz MFMA GEMM -------------------
// K=4 tau-chain, 128-element k-windows, FLAT work distribution: 136 window-
// units per batch split over 32 slots (4-5 each). Block = (slot, b); walks its
// (chain, window-range) segments, accumulates, LDS-reduces, atomicAdds to out.
// b in low 5 bits -> all blocks of a batch share an XCD (L2-resident xr).
__global__ __launch_bounds__(512, 4) void conv(
    const uint16_t* __restrict__ Wt, const uint16_t* __restrict__ xr,
    float* __restrict__ out)
{
    __shared__ uint4 lds4[LDS_TOT/16];
    char* ldsb = (char*)lds4;
    float* red = (float*)lds4;            // overlaps buf0; barrier-protected
    int tid = threadIdx.x;
    int b = blockIdx.x & 31;
    int slot = blockIdx.x >> 5;           // 0..31
    int U0 = (slot*17) >> 2;              // unit range [U0, U1)
    int U1 = ((slot+1)*17) >> 2;
    int w = tid >> 6, lane = tid & 63, n = lane & 31, hi = lane >> 5;
    int cig = w;

    // staging: 2176 idx = 2 copies x 1088 (1056 real + 32 pad); 64-idx chunks,
    // wave-uniform LDS dest (linear), per-lane global source.
    int srcE[5], dstC[5];
    #pragma unroll
    for (int k = 0; k < 5; ++k) {
        int gi = tid + (k << 9);
        if (gi < 2176) {
            int cpy = gi >= GPCP;
            int j = gi - cpy*GPCP;
            dstC[k] = cpy*CPYB + (j << 4);
            if (j < GPC) {
                int ci = (j*1986) >> 16;     // j/33 for j<1056
                int qq = j - ci*33;
                srcE[k] = (cpy ? XR_ELEMS : 0) + (b*NCI + ci)*GR + (qq << 3);
            } else srcE[k] = 0;              // pad granule: safe dummy source
        } else { srcE[k] = 0; dstC[k] = -1; }
    }

    // B-read base: o = (39 - n + 8*hi) + 16*MM; byte = ci*CIB + par*CPYB + 2*(o-par)
    int obase = 39 - n + (hi << 3);
    int par = obase & 1;
    int bbb = cig*CIB + par*CPYB + ((obase - par) << 1);

    #define STAGE(BUF, GOFF) { \
        _Pragma("unroll") \
        for (int k = 0; k < 5; ++k) \
            if (dstC[k] >= 0) gld16(xr + srcE[k] + (GOFF), (BUF) + dstC[k]); }

    int cum = 0;
    for (int c = 0; c < 16; ++c) {
        int nwc = (c < 8) ? (16 - c) : (c - 7);
        int lo = (U0 > cum) ? U0 : cum;
        int hiU = (U1 < cum + nwc) ? U1 : (cum + nwc);
        if (lo < hiU) {
            int th = (c < 8) ? (63 - (c << 2)) : ((c << 2) - 29);
            int w0 = lo - cum, w1e = hiU - cum;
            int g0base = 2016 - (th << 5);

            f32x16 acc0, acc1, acc2, acc3;
            #pragma unroll
            for (int r = 0; r < 16; ++r) { acc0[r]=0.f; acc1[r]=0.f; acc2[r]=0.f; acc3[r]=0.f; }

            __syncthreads();                 // staging region free (prior epilogue done)
            STAGE(ldsb, g0base + (w0 << 7))
            __syncthreads();

            int cur = 0;
            for (int wi = w0; wi < w1e; ++wi) {
                if (wi + 1 < w1e) {          // DMA next window into other buffer
                    char* bufn = ldsb + (cur ^ 1)*BUFB;
                    STAGE(bufn, g0base + ((wi + 1) << 7))
                }
                int dcw = wi << 4;
                const char* rbase = ldsb + cur*BUFB + bbb;

                #pragma unroll
                for (int cii = 0; cii < 4; ++cii) {
                    int ci = (cii << 3) + cig;
                    const uint16_t* aB = Wt + (((ci*WT_CH + dcw + hi)*NCO + n) << 3);
                    bf16x8 av0 = *(const bf16x8*)(aB);
                    bf16x8 av1 = *(const bf16x8*)(aB + 512);
                    bf16x8 av2 = *(const bf16x8*)(aB + 1024);
                    bf16x8 av3 = *(const bf16x8*)(aB + 1536);
                    bf16x8 av4 = *(const bf16x8*)(aB + 2048);
                    bf16x8 av5 = *(const bf16x8*)(aB + 2560);
                    bf16x8 av6 = *(const bf16x8*)(aB + 3072);
                    bf16x8 av7 = *(const bf16x8*)(aB + 3584);
                    const char* pbase = rbase + cii*(8*CIB);

                    #define RDBB(MM) union { uint32_t u_[4]; bf16x8 v; } bb; { \
                        const char* pp = pbase + ((MM) << 5); \
                        bb.u_[0] = *(const uint32_t*)(pp); \
                        bb.u_[1] = *(const uint32_t*)(pp + 4); \
                        bb.u_[2] = *(const uint32_t*)(pp + 8); \
                        bb.u_[3] = *(const uint32_t*)(pp + 12); }
                    #define MF(AC, AV) AC = __builtin_amdgcn_mfma_f32_32x32x16_bf16(AV, bb.v, AC, 0,0,0);

                    { RDBB(0)  MF(acc0, av0) }
                    { RDBB(1)  MF(acc0, av1) }
                    { RDBB(2)  MF(acc0, av2) MF(acc1, av0) }
                    { RDBB(3)  MF(acc0, av3) MF(acc1, av1) }
                    { RDBB(4)  MF(acc0, av4) MF(acc1, av2) MF(acc2, av0) }
                    { RDBB(5)  MF(acc0, av5) MF(acc1, av3) MF(acc2, av1) }
                    { RDBB(6)  MF(acc0, av6) MF(acc1, av4) MF(acc2, av2) MF(acc3, av0) }
                    { RDBB(7)  MF(acc0, av7) MF(acc1, av5) MF(acc2, av3) MF(acc3, av1) }
                    { RDBB(8)  MF(acc1, av6) MF(acc2, av4) MF(acc3, av2) }
                    { RDBB(9)  MF(acc1, av7) MF(acc2, av5) MF(acc3, av3) }
                    { RDBB(10) MF(acc2, av6) MF(acc3, av4) }
                    { RDBB(11) MF(acc2, av7) MF(acc3, av5) }
                    { RDBB(12) MF(acc3, av6) }
                    { RDBB(13) MF(acc3, av7) }
                    #undef MF
                    #undef RDBB
                }
                __syncthreads();             // drains DMA (vmcnt) + read/write fence
                cur ^= 1;
            }

            // ---- reduce across 8 ci-waves + atomic epilogue, per delta ----
            #pragma unroll
            for (int dlt = 0; dlt < 4; ++dlt) {
                f32x16 a = (dlt == 0) ? acc0 : (dlt == 1) ? acc1 : (dlt == 2) ? acc2 : acc3;
                __syncthreads();
                if (w < 4) {
                    #pragma unroll
                    for (int r = 0; r < 16; ++r)
                        red[(w*16 + r)*64 + lane] = a[r];
                }
                __syncthreads();
                if (w >= 4) {
                    #pragma unroll
                    for (int r = 0; r < 16; ++r)
                        red[((w-4)*16 + r)*64 + lane] += a[r];
                }
                __syncthreads();
                int t0 = (th - dlt) << 5;
                #pragma unroll
                for (int h = 0; h < 2; ++h) {
                    int e = tid + (h << 9);
                    int lane_e = e & 63;
                    int reg = e >> 6;
                    float s = 0.f;
                    #pragma unroll
                    for (int ww = 0; ww < 4; ++ww) s += red[(ww*16 + reg)*64 + lane_e];
                    int co = (reg & 3) + ((reg >> 2) << 3) + ((lane_e >> 5) << 2);
                    int t = t0 + (lane_e & 31);
                    atomicAdd(&out[(b*NCO + co)*T + t], s);
                }
            }
        }
        cum += nwc;
        if (cum >= U1) break;
    }
    #undef STAGE
}

extern "C" void kernel_launch(void* const* d_in, const int* in_sizes, int n_in,
                              void* d_out, int out_size, void* d_ws, size_t ws_size,
                              hipStream_t stream)
{
    const float* x       = (const float*)d_in[0];
    const float* rel_pos = (const float*)d_in[1];
    const float* w1  = (const float*)d_in[2];
    const float* b1  = (const float*)d_in[3];
    const float* om1 = (const float*)d_in[4];
    const float* w2  = (const float*)d_in[5];
    const float* b2  = (const float*)d_in[6];
    const float* om2 = (const float*)d_in[7];
    const float* w3  = (const float*)d_in[8];
    const float* b3  = (const float*)d_in[9];
    const float* bias = (const float*)d_in[10];
    float* out = (float*)d_out;
    char* ws = (char*)d_ws;
    uint16_t* Wt  = (uint16_t*)(ws + WT_OFF);
    uint16_t* xrp = (uint16_t*)(ws + XR_OFF);
    uint16_t* xrs = (uint16_t*)(ws + XRS_OFF);

    hipLaunchKernelGGL(gen_w, dim3(WT_CH*8), dim3(256), 0, stream,
                       rel_pos, w1, b1, om1, w2, b2, om2, w3, b3, Wt);
    int n2 = NB*NCI*GR;
    hipLaunchKernelGGL(gen_x, dim3((n2+255)/256), dim3(256), 0, stream, x, xrp, xrs);
    hipLaunchKernelGGL(init_out, dim3(NB*NCO*T/256), dim3(256), 0, stream, bias, out);
    hipLaunchKernelGGL(conv, dim3(NB*32), dim3(512), 0, stream, Wt, xrp, out);
}

// Round 12
// 151.350 us; speedup vs baseline: 1.3735x; 1.3735x over previous
//
#include <hip/hip_runtime.h>
#include <hip/hip_bf16.h>
#include <stdint.h>

typedef short bf16x8 __attribute__((ext_vector_type(8)));
typedef float f32x16 __attribute__((ext_vector_type(16)));

#define T 2048
#define KLEN 2049
#define DK 32
#define NCO 32
#define NCI 32
#define NB 32

#define GR 2216          // padded reversed row length (covers g up to 2184)
#define SREF 2055        // x[s] lives at g = SREF - s (xr); xrs[g] = xr[g+1]
#define WT_CH 257        // 8-wide d-chunks, d in [0,2056)
#define WT_ELEMS (NCI*WT_CH*NCO*8)
#define XR_ELEMS (NB*NCI*GR)

#define WT_OFF 0
#define XR_OFF (WT_ELEMS*2)
#define XRS_OFF (XR_OFF + XR_ELEMS*2)

#define CIB 528          // bytes per ci row: 33 x 16B granules (264 elems)
#define GPC 1056         // real granules per parity copy (32 ci x 33)
#define GPCP 1088        // padded to 17 x 64-chunks (no copy-straddle)
#define CPYB 17472       // parity-copy stride: >=GPCP*16, ==64 mod 128 (bank de-alias)
#define BUFB (2*CPYB)    // 34944 per double-buffer
#define LDS_TOT (2*BUFB) // 69888 -> 2 blocks/CU; reduce reuses buf0

// ------ kernel-generation: SIREN -> flipped, fragment-layout W (1 blk/8 d) --
__global__ __launch_bounds__(256) void gen_w(
    const float* __restrict__ rel_pos,
    const float* __restrict__ w1, const float* __restrict__ b1, const float* __restrict__ om1,
    const float* __restrict__ w2, const float* __restrict__ b2, const float* __restrict__ om2,
    const float* __restrict__ w3, const float* __restrict__ b3,
    uint16_t* __restrict__ Wt)
{
    __shared__ float h1s[8][32];
    __shared__ float h2s[8][32];
    int t = threadIdx.x;
    int dchunk = blockIdx.x;             // 0..256
    int dd = t >> 5, i = t & 31;
    int d = (dchunk << 3) + dd;
    float pos = (d < KLEN) ? rel_pos[2048 - d] : 0.f;
    h1s[dd][i] = sinf(om1[0] * (w1[i] * pos + b1[i]));
    __syncthreads();
    {
        float a = b2[i];
        #pragma unroll
        for (int j = 0; j < 32; ++j) a += w2[i*32 + j] * h1s[dd][j];
        h2s[dd][i] = sinf(om2[0] * a);
    }
    __syncthreads();
    // layer 3: each thread: 4 (ci,co) rows x 8 d's; one 16B store per row
    for (int r = 0; r < 4; ++r) {
        int tt = t + (r << 8);
        int ci = tt >> 5, co = tt & 31;
        int coci = (co << 5) + ci;       // w3 row index (co*CIN + ci)
        float w3r[32];
        #pragma unroll
        for (int j = 0; j < 8; ++j)
            *(float4*)&w3r[j*4] = *(const float4*)&w3[coci*32 + j*4];
        float bb = b3[coci];
        union { uint16_t u[8]; uint4 q; } pack;
        #pragma unroll
        for (int ddd = 0; ddd < 8; ++ddd) {
            float a = bb;
            #pragma unroll
            for (int j = 0; j < 32; ++j) a += w3r[j] * h2s[ddd][j];
            if (((dchunk << 3) + ddd) >= KLEN) a = 0.f;
            __hip_bfloat16 hv = __float2bfloat16(a);
            pack.u[ddd] = *(uint16_t*)&hv;
        }
        *(uint4*)&Wt[((ci*WT_CH + dchunk)*NCO + co) << 3] = pack.q;
    }
}

// ---------------- x -> reversed, zero-padded bf16 (plus shifted copy) -------
__global__ __launch_bounds__(256) void gen_x(const float* __restrict__ x,
                                             uint16_t* __restrict__ xr,
                                             uint16_t* __restrict__ xrs)
{
    int idx = blockIdx.x*256 + threadIdx.x;
    if (idx >= NB*NCI*GR) return;
    int row = idx / GR;          // b*32+ci
    int g = idx - row*GR;
    int s = SREF - g;
    float v  = (s  >= 0 && s  < T) ? x[row*T + s]  : 0.f;
    int s2 = s - 1;              // value at g+1
    float v2 = (s2 >= 0 && s2 < T) ? x[row*T + s2] : 0.f;
    __hip_bfloat16 hv = __float2bfloat16(v);
    __hip_bfloat16 hv2 = __float2bfloat16(v2);
    xr[idx]  = *(uint16_t*)&hv;
    xrs[idx] = *(uint16_t*)&hv2;
}

__device__ __forceinline__ void gld16(const uint16_t* g, char* l)
{
    typedef const __attribute__((address_space(1))) uint32_t GU;
    typedef __attribute__((address_space(3))) uint32_t LU;
    __builtin_amdgcn_global_load_lds((GU*)g, (LU*)l, 16, 0, 0);
}

// ---------------- causal conv: implicit-Toeplitz MFMA GEMM (r10 struct) -----
// K=4 tau-chain, 128-element k-windows. One chain per block; grid 512 = 2
// blocks/CU. Pairing: block c (long chain, 16-p windows) + c+256 (short, p+1)
// co-resident -> 17 window-units per CU. b in low 5 bits -> XCD locality.
// Per window & cii: 14 staged fragments (MM=c+2*delta) serve 32 MFMAs.
__global__ __launch_bounds__(512, 4) void conv(
    const uint16_t* __restrict__ Wt, const uint16_t* __restrict__ xr,
    const float* __restrict__ bias, float* __restrict__ out)
{
    __shared__ uint4 lds4[LDS_TOT/16];
    char* ldsb = (char*)lds4;
    float* red = (float*)lds4;            // overlaps buf0; used after final barrier
    int tid = threadIdx.x;
    int b = blockIdx.x & 31;
    int q = blockIdx.x >> 5;              // 0..15
    int p = q & 7;
    int th = (q < 8) ? (63 - (p << 2)) : ((p << 2) + 3);   // long B / short A
    int nw = (th + 1) >> 2;                                // 128-elem windows
    int g0base = 2016 - (th << 5);
    int w = tid >> 6, lane = tid & 63, n = lane & 31, hi = lane >> 5;
    int cig = w;

    // staging: 2176 idx = 2 copies x 1088 (1056 real + 32 pad); 64-idx chunks,
    // wave-uniform LDS dest (linear), per-lane global source.
    int srcE[5], dstC[5];
    #pragma unroll
    for (int k = 0; k < 5; ++k) {
        int gi = tid + (k << 9);
        if (gi < 2176) {
            int cpy = gi >= GPCP;
            int j = gi - cpy*GPCP;
            dstC[k] = cpy*CPYB + (j << 4);
            if (j < GPC) {
                int ci = (j*1986) >> 16;     // j/33 for j<1056
                int qq = j - ci*33;
                srcE[k] = (cpy ? XR_ELEMS : 0) + (b*NCI + ci)*GR + (qq << 3);
            } else srcE[k] = 0;              // pad granule: safe dummy source
        } else { srcE[k] = 0; dstC[k] = -1; }
    }

    // B-read base: o = (39 - n + 8*hi) + 16*MM; byte = ci*CIB + par*CPYB + 2*(o-par)
    int obase = 39 - n + (hi << 3);
    int par = obase & 1;
    int bbb = cig*CIB + par*CPYB + ((obase - par) << 1);

    f32x16 acc0, acc1, acc2, acc3;
    #pragma unroll
    for (int r = 0; r < 16; ++r) { acc0[r]=0.f; acc1[r]=0.f; acc2[r]=0.f; acc3[r]=0.f; }

    #define STAGE(BUF, GOFF) { \
        _Pragma("unroll") \
        for (int k = 0; k < 5; ++k) \
            if (dstC[k] >= 0) gld16(xr + srcE[k] + (GOFF), (BUF) + dstC[k]); }

    // prologue: DMA window 0 into buf0
    STAGE(ldsb, g0base)
    __syncthreads();

    for (int wi = 0; wi < nw; ++wi) {
        int cur = wi & 1;
        if (wi + 1 < nw) {                   // DMA next window into other buffer
            char* bufn = ldsb + (cur ^ 1)*BUFB;
            int g0n = g0base + ((wi + 1) << 7);
            STAGE(bufn, g0n)
        }
        int dcw = wi << 4;
        const char* rbase = ldsb + cur*BUFB + bbb;

        #pragma unroll
        for (int cii = 0; cii < 4; ++cii) {
            int ci = (cii << 3) + cig;
            const uint16_t* aB = Wt + (((ci*WT_CH + dcw + hi)*NCO + n) << 3);
            bf16x8 av0 = *(const bf16x8*)(aB);
            bf16x8 av1 = *(const bf16x8*)(aB + 512);
            bf16x8 av2 = *(const bf16x8*)(aB + 1024);
            bf16x8 av3 = *(const bf16x8*)(aB + 1536);
            bf16x8 av4 = *(const bf16x8*)(aB + 2048);
            bf16x8 av5 = *(const bf16x8*)(aB + 2560);
            bf16x8 av6 = *(const bf16x8*)(aB + 3072);
            bf16x8 av7 = *(const bf16x8*)(aB + 3584);
            const char* pbase = rbase + cii*(8*CIB);

            #define RDBB(MM) union { uint32_t u_[4]; bf16x8 v; } bb; { \
                const char* pp = pbase + ((MM) << 5); \
                bb.u_[0] = *(const uint32_t*)(pp); \
                bb.u_[1] = *(const uint32_t*)(pp + 4); \
                bb.u_[2] = *(const uint32_t*)(pp + 8); \
                bb.u_[3] = *(const uint32_t*)(pp + 12); }
            #define MF(AC, AV) AC = __builtin_amdgcn_mfma_f32_32x32x16_bf16(AV, bb.v, AC, 0,0,0);

            { RDBB(0)  MF(acc0, av0) }
            { RDBB(1)  MF(acc0, av1) }
            { RDBB(2)  MF(acc0, av2) MF(acc1, av0) }
            { RDBB(3)  MF(acc0, av3) MF(acc1, av1) }
            { RDBB(4)  MF(acc0, av4) MF(acc1, av2) MF(acc2, av0) }
            { RDBB(5)  MF(acc0, av5) MF(acc1, av3) MF(acc2, av1) }
            { RDBB(6)  MF(acc0, av6) MF(acc1, av4) MF(acc2, av2) MF(acc3, av0) }
            { RDBB(7)  MF(acc0, av7) MF(acc1, av5) MF(acc2, av3) MF(acc3, av1) }
            { RDBB(8)  MF(acc1, av6) MF(acc2, av4) MF(acc3, av2) }
            { RDBB(9)  MF(acc1, av7) MF(acc2, av5) MF(acc3, av3) }
            { RDBB(10) MF(acc2, av6) MF(acc3, av4) }
            { RDBB(11) MF(acc2, av7) MF(acc3, av5) }
            { RDBB(12) MF(acc3, av6) }
            { RDBB(13) MF(acc3, av7) }
            #undef MF
            #undef RDBB
        }
        __syncthreads();                 // drains DMA (vmcnt) + read/write fence
    }
    #undef STAGE

    // ---- reduce across 8 ci-waves + epilogue, one delta at a time ----
    #pragma unroll
    for (int dlt = 0; dlt < 4; ++dlt) {
        f32x16 a = (dlt == 0) ? acc0 : (dlt == 1) ? acc1 : (dlt == 2) ? acc2 : acc3;
        __syncthreads();
        if (w < 4) {
            #pragma unroll
            for (int r = 0; r < 16; ++r)
                red[(w*16 + r)*64 + lane] = a[r];
        }
        __syncthreads();
        if (w >= 4) {
            #pragma unroll
            for (int r = 0; r < 16; ++r)
                red[((w-4)*16 + r)*64 + lane] += a[r];
        }
        __syncthreads();
        int t0 = (th - dlt) << 5;
        #pragma unroll
        for (int h = 0; h < 2; ++h) {
            int e = tid + (h << 9);
            int lane_e = e & 63;
            int reg = e >> 6;
            float s = 0.f;
            #pragma unroll
            for (int ww = 0; ww < 4; ++ww) s += red[(ww*16 + reg)*64 + lane_e];
            int co = (reg & 3) + ((reg >> 2) << 3) + ((lane_e >> 5) << 2);
            int t = t0 + (lane_e & 31);
            out[(b*NCO + co)*T + t] = s + bias[co];
        }
    }
}

extern "C" void kernel_launch(void* const* d_in, const int* in_sizes, int n_in,
                              void* d_out, int out_size, void* d_ws, size_t ws_size,
                              hipStream_t stream)
{
    const float* x       = (const float*)d_in[0];
    const float* rel_pos = (const float*)d_in[1];
    const float* w1  = (const float*)d_in[2];
    const float* b1  = (const float*)d_in[3];
    const float* om1 = (const float*)d_in[4];
    const float* w2  = (const float*)d_in[5];
    const float* b2  = (const float*)d_in[6];
    const float* om2 = (const float*)d_in[7];
    const float* w3  = (const float*)d_in[8];
    const float* b3  = (const float*)d_in[9];
    const float* bias = (const float*)d_in[10];
    float* out = (float*)d_out;
    char* ws = (char*)d_ws;
    uint16_t* Wt  = (uint16_t*)(ws + WT_OFF);
    uint16_t* xrp = (uint16_t*)(ws + XR_OFF);
    uint16_t* xrs = (uint16_t*)(ws + XRS_OFF);

    hipLaunchKernelGGL(gen_w, dim3(WT_CH), dim3(256), 0, stream,
                       rel_pos, w1, b1, om1, w2, b2, om2, w3, b3, Wt);
    int n2 = NB*NCI*GR;
    hipLaunchKernelGGL(gen_x, dim3((n2+255)/256), dim3(256), 0, stream, x, xrp, xrs);
    hipLaunchKernelGGL(conv, dim3(NB*16), dim3(512), 0, stream, Wt, xrp, bias, out);
}